// Round 2
// baseline (731.477 us; speedup 1.0000x reference)
//
#include <hip/hip_runtime.h>

// ---------------------------------------------------------------- types/utils
using bf16x8 = __attribute__((ext_vector_type(8))) short;
using f32x4  = __attribute__((ext_vector_type(4))) float;
using u16x4  = __attribute__((ext_vector_type(4))) unsigned short;

#define AS1(p) ((__attribute__((address_space(1))) void*)(p))
#define AS3(p) ((__attribute__((address_space(3))) void*)(p))

__device__ __forceinline__ unsigned short f2bf(float f){
  unsigned int x = __float_as_uint(f);
  unsigned int r = (x + 0x7FFFu + ((x >> 16) & 1u)) >> 16;  // RNE
  return (unsigned short)r;
}
__device__ __forceinline__ float gelu_tanh(float x){
  float u = 0.7978845608028654f * (x + 0.044715f * x * x * x);
  float t = 1.f - 2.f / (__expf(2.f * u) + 1.f);   // tanh(u)
  return 0.5f * x * (1.f + t);
}

// Problem constants
static constexpr int BB = 8, LL = 768, DD = 1024, HH = 4096, TT = 6144;

// ---------------------------------------------------------------- kcvt: fp32 -> bf16
__global__ __launch_bounds__(256) void kcvt(const float* __restrict__ src,
                                            unsigned short* __restrict__ dst){
  size_t i = ((size_t)blockIdx.x * 256 + threadIdx.x);
  const float4 v = ((const float4*)src)[i];
  u16x4 o;
  o[0] = f2bf(v.x); o[1] = f2bf(v.y); o[2] = f2bf(v.z); o[3] = f2bf(v.w);
  ((u16x4*)dst)[i] = o;
}

// ---------------------------------------------------------------- K0: transpose+convert
// src (R x C) fp32 row-major -> dst (C x R) bf16 row-major. z<4: expert z, z==4: shared.
__global__ __launch_bounds__(256) void k0_transpose(const float* __restrict__ srcE,
                                                    const float* __restrict__ srcS,
                                                    unsigned short* __restrict__ dst,
                                                    int R, int C){
  __shared__ float tile[32][33];
  int z = blockIdx.z;
  const float* src = (z < 4) ? srcE + (size_t)z * R * C : srcS;
  unsigned short* d = dst + (size_t)z * R * C;
  int c0 = blockIdx.x * 32, r0 = blockIdx.y * 32;
  int tx = threadIdx.x & 31, ty = threadIdx.x >> 5;  // ty in [0,8)
  for (int rep = 0; rep < 4; rep++){
    int rr = ty + rep * 8;
    tile[rr][tx] = src[(size_t)(r0 + rr) * C + c0 + tx];
  }
  __syncthreads();
  for (int rep = 0; rep < 4; rep++){
    int a = ty + rep * 8;                      // dst row within tile (= src col)
    d[(size_t)(c0 + a) * R + r0 + tx] = f2bf(tile[tx][a]);
  }
}

// ---------------------------------------------------------------- K1a: segment partial sums
// part[b][chunk(12)][d(1024)] fp32, chunk = 64 tokens
__global__ __launch_bounds__(256) void k1a_partial(const float* __restrict__ X,
                                                   float* __restrict__ part){
  int ch = blockIdx.x, b = blockIdx.y, t = threadIdx.x;
  const float* base = X + ((size_t)(b * LL + ch * 64)) * DD;
  float s0 = 0.f, s1 = 0.f, s2 = 0.f, s3 = 0.f;
  for (int l = 0; l < 64; l++){
    const float* row = base + (size_t)l * DD;
    s0 += row[t];
    s1 += row[256 + t];
    s2 += row[512 + t];
    s3 += row[768 + t];
  }
  float* p = part + ((size_t)(b * 12 + ch)) * DD;
  p[t] = s0; p[256 + t] = s1; p[512 + t] = s2; p[768 + t] = s3;
}

// ---------------------------------------------------------------- K1b: gating finalize (fp32)
__global__ __launch_bounds__(256) void k1b_gate(const float* __restrict__ part,
                                                const float* __restrict__ tc,
                                                const float* __restrict__ gw,
                                                const float* __restrict__ gb,
                                                const float* __restrict__ tw,
                                                const float* __restrict__ tb,
                                                float* __restrict__ wtop, int* __restrict__ itop){
  int b = blockIdx.x, t = threadIdx.x;
  __shared__ float glog[4], gmod[8];
  if (t < 4) glog[t] = 0.f;
  if (t < 8) gmod[t] = 0.f;
  __syncthreads();
  float lacc[4] = {0.f,0.f,0.f,0.f};
  float macc[8] = {0.f,0.f,0.f,0.f,0.f,0.f,0.f,0.f};
  for (int dd = 0; dd < 4; dd++){
    int d = dd * 256 + t;
    const float* pb = part + (size_t)b * 12 * DD + d;
    float sh = 0.f, sw = 0.f, sp = 0.f;
    for (int c2 = 0; c2 < 4; c2++){
      sh += pb[(0 + c2) * DD];
      sw += pb[(4 + c2) * DD];
      sp += pb[(8 + c2) * DD];
    }
    float fa = (sh + sw + sp) * (1.f / 768.f);
    float hp = (sh + sp) * (1.f / 512.f);
    float wp = (sw + sp) * (1.f / 512.f);
    #pragma unroll
    for (int e = 0; e < 4; e++){
      lacc[e] += fa * gw[(size_t)d * 4 + e]
               + hp * gw[(size_t)(DD + d) * 4 + e]
               + wp * gw[(size_t)(2 * DD + d) * 4 + e];
    }
    float v = tc[(size_t)b * DD + d];
    float sl = v / (1.f + __expf(-v));           // silu
    #pragma unroll
    for (int j = 0; j < 8; j++) macc[j] += sl * tw[(size_t)d * 8 + j];
  }
  #pragma unroll
  for (int e = 0; e < 4; e++) atomicAdd(&glog[e], lacc[e]);
  #pragma unroll
  for (int j = 0; j < 8; j++) atomicAdd(&gmod[j], macc[j]);
  __syncthreads();
  if (t == 0){
    float lg[4];
    #pragma unroll
    for (int e = 0; e < 4; e++){
      float sc = gmod[e]     + tb[e];      // scale
      float sf = gmod[4 + e] + tb[4 + e];  // shift
      lg[e] = (glog[e] + gb[e]) * (1.f + sc) + sf;
    }
    float mx = fmaxf(fmaxf(lg[0], lg[1]), fmaxf(lg[2], lg[3]));
    float p[4], s = 0.f;
    #pragma unroll
    for (int e = 0; e < 4; e++){ p[e] = __expf(lg[e] - mx); s += p[e]; }
    #pragma unroll
    for (int e = 0; e < 4; e++) p[e] /= s;
    int i0 = 0;
    for (int e = 1; e < 4; e++) if (p[e] > p[i0]) i0 = e;
    int i1 = (i0 == 0) ? 1 : 0;
    for (int e = 0; e < 4; e++) if (e != i0 && p[e] > p[i1]) i1 = e;
    float den = p[i0] + p[i1] + 1e-8f;
    wtop[b * 2 + 0] = p[i0] / den;  wtop[b * 2 + 1] = p[i1] / den;
    itop[b * 2 + 0] = i0;           itop[b * 2 + 1] = i1;
  }
}

// ---------------------------------------------------------------- GEMM core
// C(128x128) += A(128 x 64*nkt) * B^T; A rows K-contig (lda), B rows (=output
// cols) K-contig (ldb). Both bf16. 256 thr = 4 waves 2x2; wave tile 64x64 =
// 4x4 MFMA 16x16x32 tiles. LDS cell = 16B; XOR swizzle c^=(m&7) so the
// fragment ds_read_b128 is 2-way bank aliased (free) instead of 16-way.
__device__ __forceinline__ void gemm_core(const unsigned short* __restrict__ A,
                                          const unsigned short* __restrict__ B,
                                          size_t lda, size_t ldb, int nkt,
                                          unsigned short* ldsA, unsigned short* ldsB,
                                          f32x4 (&acc)[4][4]){
  int tid = threadIdx.x;
  int lane = tid & 63, wave = tid >> 6;
  int quad = lane >> 4, r = lane & 15;
  int wm = (wave >> 1) * 64, wn = (wave & 1) * 64;
  int wavebase = tid & 192;                       // wave*64, wave-uniform
  for (int kt = 0; kt < nkt; kt++){
    int k0 = kt * 64;
    #pragma unroll
    for (int i = 0; i < 4; i++){
      int g = i * 256 + tid;                      // cell index [0,1024)
      int m = g >> 3, slot = g & 7;
      int c = slot ^ (m & 7);
      const unsigned short* gpA = A + (size_t)m * lda + (k0 + c * 8);
      const unsigned short* gpB = B + (size_t)m * ldb + (k0 + c * 8);
      unsigned short* lp = ldsA + (size_t)(i * 256 + wavebase) * 8; // wave-uniform
      __builtin_amdgcn_global_load_lds(AS1(gpA), AS3(lp), 16, 0, 0);
      unsigned short* lq = ldsB + (size_t)(i * 256 + wavebase) * 8;
      __builtin_amdgcn_global_load_lds(AS1(gpB), AS3(lq), 16, 0, 0);
    }
    __syncthreads();
    #pragma unroll
    for (int ks = 0; ks < 2; ks++){
      int cc = ks * 4 + quad;
      bf16x8 af[4], bfv[4];
      #pragma unroll
      for (int t2 = 0; t2 < 4; t2++){
        int m = wm + t2 * 16 + r;
        af[t2] = *(const bf16x8*)(ldsA + ((size_t)m * 8 + (cc ^ (m & 7))) * 8);
        int n = wn + t2 * 16 + r;
        bfv[t2] = *(const bf16x8*)(ldsB + ((size_t)n * 8 + (cc ^ (n & 7))) * 8);
      }
      #pragma unroll
      for (int mi = 0; mi < 4; mi++)
        #pragma unroll
        for (int ni = 0; ni < 4; ni++)
          acc[mi][ni] = __builtin_amdgcn_mfma_f32_16x16x32_bf16(af[mi], bfv[ni], acc[mi][ni], 0, 0, 0);
    }
    __syncthreads();
  }
}

__device__ __forceinline__ void mask_weight(int e, int seg, float& w){
  if ((e == 1 && seg == 1) || (e == 2 && seg == 0)) w = 0.f;
}

// ---------------------------------------------------------------- K2: GEMM1 + gelu
// H[slot][token][h] = w_eff * gelu(X @ W1 + b1). slot0=shared(w=1), slot1/2=topk.
__global__ __launch_bounds__(256) void k2_gemm1(const unsigned short* __restrict__ Xb,
                                                const unsigned short* __restrict__ w1t,
                                                const float* __restrict__ eb1,
                                                const float* __restrict__ sb1,
                                                const float* __restrict__ wtop,
                                                const int* __restrict__ itop,
                                                unsigned short* __restrict__ Hws){
  int m0 = blockIdx.x * 128, n0 = blockIdx.y * 128, slot = blockIdx.z;
  int b = m0 / LL, seg = (m0 % LL) / 256;
  int mat; float w;
  if (slot == 0){ mat = 4; w = 1.f; }
  else {
    int k = slot - 1;
    mat = itop[b * 2 + k];
    w = wtop[b * 2 + k];
    mask_weight(mat, seg, w);
    if (w == 0.f) return;  // K3 skips this (m-tile, slot) with the same predicate
  }
  __shared__ __align__(16) unsigned short ldsA[128 * 64];
  __shared__ __align__(16) unsigned short ldsB[128 * 64];
  f32x4 acc[4][4];
  #pragma unroll
  for (int mi = 0; mi < 4; mi++)
    #pragma unroll
    for (int ni = 0; ni < 4; ni++)
      #pragma unroll
      for (int c = 0; c < 4; c++) acc[mi][ni][c] = 0.f;

  const unsigned short* Abase = Xb + (size_t)m0 * DD;
  const unsigned short* Bbase = w1t + (size_t)mat * HH * DD + (size_t)n0 * DD;
  gemm_core(Abase, Bbase, DD, DD, DD / 64, ldsA, ldsB, acc);

  int tid = threadIdx.x, lane = tid & 63, wave = tid >> 6;
  int quad = lane >> 4, r = lane & 15;
  int wm = (wave >> 1) * 64, wn = (wave & 1) * 64;
  const float* b1 = (mat == 4) ? sb1 : eb1 + (size_t)mat * HH;
  unsigned short* Hout = Hws + (size_t)slot * TT * HH;
  #pragma unroll
  for (int ni = 0; ni < 4; ni++){
    int col = n0 + wn + ni * 16 + r;
    float bias = b1[col];
    #pragma unroll
    for (int mi = 0; mi < 4; mi++){
      #pragma unroll
      for (int r2 = 0; r2 < 4; r2++){
        int row = m0 + wm + mi * 16 + quad * 4 + r2;
        float v = gelu_tanh(acc[mi][ni][r2] + bias) * w;
        Hout[(size_t)row * HH + col] = f2bf(v);
      }
    }
  }
}

// ---------------------------------------------------------------- K3: GEMM2 + bias (fp32 out)
__global__ __launch_bounds__(256) void k3_gemm2(const unsigned short* __restrict__ Hws,
                                                const unsigned short* __restrict__ w2t,
                                                const float* __restrict__ eb2,
                                                const float* __restrict__ sb2,
                                                const float* __restrict__ wtop,
                                                const int* __restrict__ itop,
                                                float* __restrict__ out){
  int m0 = blockIdx.x * 128, n0 = blockIdx.y * 128;
  int b = m0 / LL, seg = (m0 % LL) / 256;
  __shared__ __align__(16) unsigned short ldsA[128 * 64];
  __shared__ __align__(16) unsigned short ldsB[128 * 64];
  f32x4 acc[4][4];
  #pragma unroll
  for (int mi = 0; mi < 4; mi++)
    #pragma unroll
    for (int ni = 0; ni < 4; ni++)
      #pragma unroll
      for (int c = 0; c < 4; c++) acc[mi][ni][c] = 0.f;

  int emat[2]; float ew[2];
  #pragma unroll
  for (int k = 0; k < 2; k++){
    emat[k] = itop[b * 2 + k];
    ew[k] = wtop[b * 2 + k];
    mask_weight(emat[k], seg, ew[k]);
  }
  for (int slot = 0; slot < 3; slot++){
    int mat;
    if (slot == 0) mat = 4;
    else { if (ew[slot - 1] == 0.f) continue; mat = emat[slot - 1]; }
    const unsigned short* Abase = Hws + (size_t)slot * TT * HH + (size_t)m0 * HH;
    const unsigned short* Bbase = w2t + (size_t)mat * DD * HH + (size_t)n0 * HH;
    gemm_core(Abase, Bbase, HH, HH, HH / 64, ldsA, ldsB, acc);
  }
  int tid = threadIdx.x, lane = tid & 63, wave = tid >> 6;
  int quad = lane >> 4, r = lane & 15;
  int wm = (wave >> 1) * 64, wn = (wave & 1) * 64;
  #pragma unroll
  for (int ni = 0; ni < 4; ni++){
    int col = n0 + wn + ni * 16 + r;
    float bias = sb2[col];
    if (ew[0] > 0.f) bias += ew[0] * eb2[(size_t)emat[0] * DD + col];
    if (ew[1] > 0.f) bias += ew[1] * eb2[(size_t)emat[1] * DD + col];
    #pragma unroll
    for (int mi = 0; mi < 4; mi++){
      #pragma unroll
      for (int r2 = 0; r2 < 4; r2++){
        int row = m0 + wm + mi * 16 + quad * 4 + r2;
        out[(size_t)row * DD + col] = acc[mi][ni][r2] + bias;
      }
    }
  }
}

// ---------------------------------------------------------------- launch
extern "C" void kernel_launch(void* const* d_in, const int* in_sizes, int n_in,
                              void* d_out, int out_size, void* d_ws, size_t ws_size,
                              hipStream_t stream){
  const float* X   = (const float*)d_in[0];   // context_c (8,768,1024)
  const float* tc  = (const float*)d_in[1];   // time_cond (8,1024)
  const float* gw  = (const float*)d_in[2];   // gate_w (3072,4)
  const float* gb  = (const float*)d_in[3];   // gate_b (4)
  const float* tw  = (const float*)d_in[4];   // time_w (1024,8)
  const float* tb  = (const float*)d_in[5];   // time_b (8)
  const float* ew1 = (const float*)d_in[6];   // (4,1024,4096)
  const float* eb1 = (const float*)d_in[7];   // (4,4096)
  const float* ew2 = (const float*)d_in[8];   // (4,4096,1024)
  const float* eb2 = (const float*)d_in[9];   // (4,1024)
  const float* sw1 = (const float*)d_in[10];  // (1024,4096)
  const float* sb1 = (const float*)d_in[11];  // (4096)
  const float* sw2 = (const float*)d_in[12];  // (4096,1024)
  const float* sb2 = (const float*)d_in[13];  // (1024)
  float* out = (float*)d_out;
  char* ws = (char*)d_ws;

  const size_t off_part = 0;                         // 8*12*1024*4 = 393216
  const size_t off_wtop = 393216;                    // 64 B
  const size_t off_itop = 393344;                    // 64 B
  const size_t off_xb   = 1ull << 20;                // 6144*1024*2 = 12,582,912
  const size_t off_w1t  = 14ull << 20;               // 5*4096*1024*2 = 41,943,040
  const size_t off_w2t  = off_w1t + 41943040ull;     // 41,943,040
  const size_t off_h    = off_w2t + 41943040ull;     // 3*6144*4096*2 = 150,994,944
  const size_t need     = off_h + 150994944ull;      // ~238 MiB
  if (ws_size < need) return;  // diagnostic: reproduces stub absmax 3.34375 if ws too small

  float* part = (float*)(ws + off_part);
  float* wtop = (float*)(ws + off_wtop);
  int*   itop = (int*)(ws + off_itop);
  unsigned short* Xb  = (unsigned short*)(ws + off_xb);
  unsigned short* w1t = (unsigned short*)(ws + off_w1t);
  unsigned short* w2t = (unsigned short*)(ws + off_w2t);
  unsigned short* Hws = (unsigned short*)(ws + off_h);

  // X fp32 -> bf16 (6144*1024 elements, 4/thread)
  kcvt<<<dim3(6144), 256, 0, stream>>>(X, Xb);
  // K0: weight transpose+convert (W1: 1024x4096 -> 4096x1024; W2: 4096x1024 -> 1024x4096)
  k0_transpose<<<dim3(128, 32, 5), 256, 0, stream>>>(ew1, sw1, w1t, 1024, 4096);
  k0_transpose<<<dim3(32, 128, 5), 256, 0, stream>>>(ew2, sw2, w2t, 4096, 1024);
  // K1: gating (fp32 exact)
  k1a_partial<<<dim3(12, 8), 256, 0, stream>>>(X, part);
  k1b_gate<<<dim3(8), 256, 0, stream>>>(part, tc, gw, gb, tw, tb, wtop, itop);
  // K2: X @ W1 + b1 -> gelu -> *w_eff -> H (3 slots)
  k2_gemm1<<<dim3(48, 32, 3), 256, 0, stream>>>(Xb, w1t, eb1, sb1, wtop, itop, Hws);
  // K3: sum_slots H @ W2 + biases -> out (fp32)
  k3_gemm2<<<dim3(48, 8), 256, 0, stream>>>(Hws, w2t, eb2, sb2, wtop, itop, out);
}

// Round 3
// 708.649 us; speedup vs baseline: 1.0322x; 1.0322x over previous
//
#include <hip/hip_runtime.h>

// ---------------------------------------------------------------- types/utils
using bf16x8 = __attribute__((ext_vector_type(8))) short;
using f32x4  = __attribute__((ext_vector_type(4))) float;
using u16x4  = __attribute__((ext_vector_type(4))) unsigned short;

#define AS1(p) ((__attribute__((address_space(1))) void*)(p))
#define AS3(p) ((__attribute__((address_space(3))) void*)(p))

__device__ __forceinline__ unsigned short f2bf(float f){
  unsigned int x = __float_as_uint(f);
  unsigned int r = (x + 0x7FFFu + ((x >> 16) & 1u)) >> 16;  // RNE
  return (unsigned short)r;
}
__device__ __forceinline__ float gelu_tanh(float x){
  float u = 0.7978845608028654f * (x + 0.044715f * x * x * x);
  float t = 1.f - 2.f / (__expf(2.f * u) + 1.f);   // tanh(u)
  return 0.5f * x * (1.f + t);
}

// Problem constants
static constexpr int BB = 8, LL = 768, DD = 1024, HH = 4096, TT = 6144;

// ---------------------------------------------------------------- K0: transpose+convert
// src (R x C) fp32 row-major -> dst (C x R) bf16 row-major. z<4: expert z, z==4: shared.
__global__ __launch_bounds__(256) void k0_transpose(const float* __restrict__ srcE,
                                                    const float* __restrict__ srcS,
                                                    unsigned short* __restrict__ dst,
                                                    int R, int C){
  __shared__ float tile[32][33];
  int z = blockIdx.z;
  const float* src = (z < 4) ? srcE + (size_t)z * R * C : srcS;
  unsigned short* d = dst + (size_t)z * R * C;
  int c0 = blockIdx.x * 32, r0 = blockIdx.y * 32;
  int tx = threadIdx.x & 31, ty = threadIdx.x >> 5;  // ty in [0,8)
  for (int rep = 0; rep < 4; rep++){
    int rr = ty + rep * 8;
    tile[rr][tx] = src[(size_t)(r0 + rr) * C + c0 + tx];
  }
  __syncthreads();
  for (int rep = 0; rep < 4; rep++){
    int a = ty + rep * 8;                      // dst row within tile (= src col)
    d[(size_t)(c0 + a) * R + r0 + tx] = f2bf(tile[tx][a]);
  }
}

// ---------------------------------------------------------------- K1x: X->bf16 + segment partial sums
// One pass over X: emits Xb (bf16) and part[b][chunk(12)][d(1024)] fp32 (chunk=64 tokens).
__global__ __launch_bounds__(256) void k1x_cvt_partial(const float* __restrict__ X,
                                                       unsigned short* __restrict__ Xb,
                                                       float* __restrict__ part){
  int ch = blockIdx.x, b = blockIdx.y, t = threadIdx.x;
  size_t rowbase = ((size_t)(b * LL + ch * 64)) * DD;
  const float4* src = (const float4*)(X + rowbase);
  u16x4* dst = (u16x4*)(Xb + rowbase);
  float4 s; s.x = s.y = s.z = s.w = 0.f;
  for (int l = 0; l < 64; l++){
    float4 v = src[l * 256 + t];
    u16x4 o;
    o[0] = f2bf(v.x); o[1] = f2bf(v.y); o[2] = f2bf(v.z); o[3] = f2bf(v.w);
    dst[l * 256 + t] = o;
    s.x += v.x; s.y += v.y; s.z += v.z; s.w += v.w;
  }
  ((float4*)(part + ((size_t)(b * 12 + ch)) * DD))[t] = s;
}

// ---------------------------------------------------------------- K1b: gating finalize (fp32)
__global__ __launch_bounds__(256) void k1b_gate(const float* __restrict__ part,
                                                const float* __restrict__ tc,
                                                const float* __restrict__ gw,
                                                const float* __restrict__ gb,
                                                const float* __restrict__ tw,
                                                const float* __restrict__ tb,
                                                float* __restrict__ wtop, int* __restrict__ itop){
  int b = blockIdx.x, t = threadIdx.x;
  __shared__ float glog[4], gmod[8];
  if (t < 4) glog[t] = 0.f;
  if (t < 8) gmod[t] = 0.f;
  __syncthreads();
  float lacc[4] = {0.f,0.f,0.f,0.f};
  float macc[8] = {0.f,0.f,0.f,0.f,0.f,0.f,0.f,0.f};
  for (int dd = 0; dd < 4; dd++){
    int d = dd * 256 + t;
    const float* pb = part + (size_t)b * 12 * DD + d;
    float sh = 0.f, sw = 0.f, sp = 0.f;
    for (int c2 = 0; c2 < 4; c2++){
      sh += pb[(0 + c2) * DD];
      sw += pb[(4 + c2) * DD];
      sp += pb[(8 + c2) * DD];
    }
    float fa = (sh + sw + sp) * (1.f / 768.f);
    float hp = (sh + sp) * (1.f / 512.f);
    float wp = (sw + sp) * (1.f / 512.f);
    #pragma unroll
    for (int e = 0; e < 4; e++){
      lacc[e] += fa * gw[(size_t)d * 4 + e]
               + hp * gw[(size_t)(DD + d) * 4 + e]
               + wp * gw[(size_t)(2 * DD + d) * 4 + e];
    }
    float v = tc[(size_t)b * DD + d];
    float sl = v / (1.f + __expf(-v));           // silu
    #pragma unroll
    for (int j = 0; j < 8; j++) macc[j] += sl * tw[(size_t)d * 8 + j];
  }
  #pragma unroll
  for (int e = 0; e < 4; e++) atomicAdd(&glog[e], lacc[e]);
  #pragma unroll
  for (int j = 0; j < 8; j++) atomicAdd(&gmod[j], macc[j]);
  __syncthreads();
  if (t == 0){
    float lg[4];
    #pragma unroll
    for (int e = 0; e < 4; e++){
      float sc = gmod[e]     + tb[e];      // scale
      float sf = gmod[4 + e] + tb[4 + e];  // shift
      lg[e] = (glog[e] + gb[e]) * (1.f + sc) + sf;
    }
    float mx = fmaxf(fmaxf(lg[0], lg[1]), fmaxf(lg[2], lg[3]));
    float p[4], s = 0.f;
    #pragma unroll
    for (int e = 0; e < 4; e++){ p[e] = __expf(lg[e] - mx); s += p[e]; }
    #pragma unroll
    for (int e = 0; e < 4; e++) p[e] /= s;
    int i0 = 0;
    for (int e = 1; e < 4; e++) if (p[e] > p[i0]) i0 = e;
    int i1 = (i0 == 0) ? 1 : 0;
    for (int e = 0; e < 4; e++) if (e != i0 && p[e] > p[i1]) i1 = e;
    float den = p[i0] + p[i1] + 1e-8f;
    wtop[b * 2 + 0] = p[i0] / den;  wtop[b * 2 + 1] = p[i1] / den;
    itop[b * 2 + 0] = i0;           itop[b * 2 + 1] = i1;
  }
}

// ---------------------------------------------------------------- GEMM core
// C(128x128) += A(128 x 64*nkt) * B^T; A rows K-contig (lda), B rows (=output
// cols) K-contig (ldb). Both bf16. 256 thr = 4 waves 2x2; wave tile 64x64 =
// 4x4 MFMA 16x16x32 tiles. LDS cell = 16B; XOR swizzle c^=(m&7) so the
// fragment ds_read_b128 is 2-way bank aliased (free) instead of 16-way.
__device__ __forceinline__ void gemm_core(const unsigned short* __restrict__ A,
                                          const unsigned short* __restrict__ B,
                                          size_t lda, size_t ldb, int nkt,
                                          unsigned short* ldsA, unsigned short* ldsB,
                                          f32x4 (&acc)[4][4]){
  int tid = threadIdx.x;
  int lane = tid & 63, wave = tid >> 6;
  int quad = lane >> 4, r = lane & 15;
  int wm = (wave >> 1) * 64, wn = (wave & 1) * 64;
  int wavebase = tid & 192;                       // wave*64, wave-uniform
  for (int kt = 0; kt < nkt; kt++){
    int k0 = kt * 64;
    #pragma unroll
    for (int i = 0; i < 4; i++){
      int g = i * 256 + tid;                      // cell index [0,1024)
      int m = g >> 3, slot = g & 7;
      int c = slot ^ (m & 7);
      const unsigned short* gpA = A + (size_t)m * lda + (k0 + c * 8);
      const unsigned short* gpB = B + (size_t)m * ldb + (k0 + c * 8);
      unsigned short* lp = ldsA + (size_t)(i * 256 + wavebase) * 8; // wave-uniform
      __builtin_amdgcn_global_load_lds(AS1(gpA), AS3(lp), 16, 0, 0);
      unsigned short* lq = ldsB + (size_t)(i * 256 + wavebase) * 8;
      __builtin_amdgcn_global_load_lds(AS1(gpB), AS3(lq), 16, 0, 0);
    }
    __syncthreads();
    #pragma unroll
    for (int ks = 0; ks < 2; ks++){
      int cc = ks * 4 + quad;
      bf16x8 af[4], bfv[4];
      #pragma unroll
      for (int t2 = 0; t2 < 4; t2++){
        int m = wm + t2 * 16 + r;
        af[t2] = *(const bf16x8*)(ldsA + ((size_t)m * 8 + (cc ^ (m & 7))) * 8);
        int n = wn + t2 * 16 + r;
        bfv[t2] = *(const bf16x8*)(ldsB + ((size_t)n * 8 + (cc ^ (n & 7))) * 8);
      }
      #pragma unroll
      for (int mi = 0; mi < 4; mi++)
        #pragma unroll
        for (int ni = 0; ni < 4; ni++)
          acc[mi][ni] = __builtin_amdgcn_mfma_f32_16x16x32_bf16(af[mi], bfv[ni], acc[mi][ni], 0, 0, 0);
    }
    __syncthreads();
  }
}

__device__ __forceinline__ void mask_weight(int e, int seg, float& w){
  if ((e == 1 && seg == 1) || (e == 2 && seg == 0)) w = 0.f;
}

// ---------------------------------------------------------------- K2: GEMM1 + gelu
// H[slot][token][h] = w_eff * gelu(X @ W1 + b1). slot0=shared(w=1), slot1/2=topk.
__global__ __launch_bounds__(256) void k2_gemm1(const unsigned short* __restrict__ Xb,
                                                const unsigned short* __restrict__ w1t,
                                                const float* __restrict__ eb1,
                                                const float* __restrict__ sb1,
                                                const float* __restrict__ wtop,
                                                const int* __restrict__ itop,
                                                unsigned short* __restrict__ Hws){
  int m0 = blockIdx.x * 128, n0 = blockIdx.y * 128, slot = blockIdx.z;
  int b = m0 / LL, seg = (m0 % LL) / 256;
  int mat; float w;
  if (slot == 0){ mat = 4; w = 1.f; }
  else {
    int k = slot - 1;
    mat = itop[b * 2 + k];
    w = wtop[b * 2 + k];
    mask_weight(mat, seg, w);
    if (w == 0.f) return;  // K3a skips this (m-tile, slot) with the same predicate
  }
  __shared__ __align__(16) unsigned short ldsA[128 * 64];
  __shared__ __align__(16) unsigned short ldsB[128 * 64];
  f32x4 acc[4][4];
  #pragma unroll
  for (int mi = 0; mi < 4; mi++)
    #pragma unroll
    for (int ni = 0; ni < 4; ni++)
      #pragma unroll
      for (int c = 0; c < 4; c++) acc[mi][ni][c] = 0.f;

  const unsigned short* Abase = Xb + (size_t)m0 * DD;
  const unsigned short* Bbase = w1t + (size_t)mat * HH * DD + (size_t)n0 * DD;
  gemm_core(Abase, Bbase, DD, DD, DD / 64, ldsA, ldsB, acc);

  int tid = threadIdx.x, lane = tid & 63, wave = tid >> 6;
  int quad = lane >> 4, r = lane & 15;
  int wm = (wave >> 1) * 64, wn = (wave & 1) * 64;
  const float* b1 = (mat == 4) ? sb1 : eb1 + (size_t)mat * HH;
  unsigned short* Hout = Hws + (size_t)slot * TT * HH;
  #pragma unroll
  for (int ni = 0; ni < 4; ni++){
    int col = n0 + wn + ni * 16 + r;
    float bias = b1[col];
    #pragma unroll
    for (int mi = 0; mi < 4; mi++){
      #pragma unroll
      for (int r2 = 0; r2 < 4; r2++){
        int row = m0 + wm + mi * 16 + quad * 4 + r2;
        float v = gelu_tanh(acc[mi][ni][r2] + bias) * w;
        Hout[(size_t)row * HH + col] = f2bf(v);
      }
    }
  }
}

// ---------------------------------------------------------------- K3z: out = sb2 + sum_k w_k*eb2[e_k]
// Runs before k3a; gives atomics a defined base (no inter-block ordering needed).
__global__ __launch_bounds__(256) void k3z_bias(const float* __restrict__ sb2,
                                                const float* __restrict__ eb2,
                                                const float* __restrict__ wtop,
                                                const int* __restrict__ itop,
                                                float* __restrict__ out){
  int idx = blockIdx.x * 256 + threadIdx.x;    // one float4 per thread
  int row = idx >> 8;                          // 256 float4s per row
  int c4 = (idx & 255) * 4;
  int b = row / LL, seg = (row % LL) / 256;
  float w0 = wtop[b * 2 + 0], w1 = wtop[b * 2 + 1];
  int e0 = itop[b * 2 + 0], e1 = itop[b * 2 + 1];
  mask_weight(e0, seg, w0); mask_weight(e1, seg, w1);
  float4 v = *(const float4*)(sb2 + c4);
  if (w0 > 0.f){
    const float* p = eb2 + (size_t)e0 * DD + c4;
    v.x += w0 * p[0]; v.y += w0 * p[1]; v.z += w0 * p[2]; v.w += w0 * p[3];
  }
  if (w1 > 0.f){
    const float* p = eb2 + (size_t)e1 * DD + c4;
    v.x += w1 * p[0]; v.y += w1 * p[1]; v.z += w1 * p[2]; v.w += w1 * p[3];
  }
  *(float4*)(out + (size_t)row * DD + c4) = v;
}

// ---------------------------------------------------------------- K3a: GEMM2 split (slot x K-half), atomic accumulate
__global__ __launch_bounds__(256) void k3a_gemm2(const unsigned short* __restrict__ Hws,
                                                 const unsigned short* __restrict__ w2t,
                                                 const float* __restrict__ wtop,
                                                 const int* __restrict__ itop,
                                                 float* __restrict__ out){
  int m0 = blockIdx.x * 128, n0 = blockIdx.y * 128;
  int slot = blockIdx.z >> 1, kh = blockIdx.z & 1;   // K half: [0,2048) or [2048,4096)
  int b = m0 / LL, seg = (m0 % LL) / 256;
  int mat;
  if (slot == 0) mat = 4;
  else {
    int k = slot - 1;
    mat = itop[b * 2 + k];
    float w = wtop[b * 2 + k];
    mask_weight(mat, seg, w);
    if (w == 0.f) return;                            // matching K2 skip: H tile never written
  }
  __shared__ __align__(16) unsigned short ldsA[128 * 64];
  __shared__ __align__(16) unsigned short ldsB[128 * 64];
  f32x4 acc[4][4];
  #pragma unroll
  for (int mi = 0; mi < 4; mi++)
    #pragma unroll
    for (int ni = 0; ni < 4; ni++)
      #pragma unroll
      for (int c = 0; c < 4; c++) acc[mi][ni][c] = 0.f;

  const unsigned short* Abase = Hws + (size_t)slot * TT * HH + (size_t)m0 * HH + kh * 2048;
  const unsigned short* Bbase = w2t + (size_t)mat * DD * HH + (size_t)n0 * HH + kh * 2048;
  gemm_core(Abase, Bbase, HH, HH, 2048 / 64, ldsA, ldsB, acc);

  int tid = threadIdx.x, lane = tid & 63, wave = tid >> 6;
  int quad = lane >> 4, r = lane & 15;
  int wm = (wave >> 1) * 64, wn = (wave & 1) * 64;
  #pragma unroll
  for (int ni = 0; ni < 4; ni++){
    int col = n0 + wn + ni * 16 + r;
    #pragma unroll
    for (int mi = 0; mi < 4; mi++){
      #pragma unroll
      for (int r2 = 0; r2 < 4; r2++){
        int row = m0 + wm + mi * 16 + quad * 4 + r2;
        unsafeAtomicAdd(&out[(size_t)row * DD + col], acc[mi][ni][r2]);
      }
    }
  }
}

// ---------------------------------------------------------------- launch
extern "C" void kernel_launch(void* const* d_in, const int* in_sizes, int n_in,
                              void* d_out, int out_size, void* d_ws, size_t ws_size,
                              hipStream_t stream){
  const float* X   = (const float*)d_in[0];   // context_c (8,768,1024)
  const float* tc  = (const float*)d_in[1];   // time_cond (8,1024)
  const float* gw  = (const float*)d_in[2];   // gate_w (3072,4)
  const float* gb  = (const float*)d_in[3];   // gate_b (4)
  const float* tw  = (const float*)d_in[4];   // time_w (1024,8)
  const float* tb  = (const float*)d_in[5];   // time_b (8)
  const float* ew1 = (const float*)d_in[6];   // (4,1024,4096)
  const float* eb1 = (const float*)d_in[7];   // (4,4096)
  const float* ew2 = (const float*)d_in[8];   // (4,4096,1024)
  const float* eb2 = (const float*)d_in[9];   // (4,1024)
  const float* sw1 = (const float*)d_in[10];  // (1024,4096)
  const float* sb1 = (const float*)d_in[11];  // (4096)
  const float* sw2 = (const float*)d_in[12];  // (4096,1024)
  const float* sb2 = (const float*)d_in[13];  // (1024)
  float* out = (float*)d_out;
  char* ws = (char*)d_ws;

  const size_t off_part = 0;                         // 8*12*1024*4 = 393216
  const size_t off_wtop = 393216;                    // 64 B
  const size_t off_itop = 393344;                    // 64 B
  const size_t off_xb   = 1ull << 20;                // 6144*1024*2 = 12,582,912
  const size_t off_w1t  = 14ull << 20;               // 5*4096*1024*2 = 41,943,040
  const size_t off_w2t  = off_w1t + 41943040ull;     // 41,943,040
  const size_t off_h    = off_w2t + 41943040ull;     // 3*6144*4096*2 = 150,994,944
  const size_t need     = off_h + 150994944ull;      // ~238 MiB
  if (ws_size < need) return;  // diagnostic: reproduces stub absmax 3.34375 if ws too small

  float* part = (float*)(ws + off_part);
  float* wtop = (float*)(ws + off_wtop);
  int*   itop = (int*)(ws + off_itop);
  unsigned short* Xb  = (unsigned short*)(ws + off_xb);
  unsigned short* w1t = (unsigned short*)(ws + off_w1t);
  unsigned short* w2t = (unsigned short*)(ws + off_w2t);
  unsigned short* Hws = (unsigned short*)(ws + off_h);

  // K1x: X fp32 -> bf16 + gating partial sums (single pass over X)
  k1x_cvt_partial<<<dim3(12, 8), 256, 0, stream>>>(X, Xb, part);
  // K0: weight transpose+convert (W1: 1024x4096 -> 4096x1024; W2: 4096x1024 -> 1024x4096)
  k0_transpose<<<dim3(128, 32, 5), 256, 0, stream>>>(ew1, sw1, w1t, 1024, 4096);
  k0_transpose<<<dim3(32, 128, 5), 256, 0, stream>>>(ew2, sw2, w2t, 4096, 1024);
  // K1b: gating finalize (fp32 exact)
  k1b_gate<<<dim3(8), 256, 0, stream>>>(part, tc, gw, gb, tw, tb, wtop, itop);
  // K2: X @ W1 + b1 -> gelu -> *w_eff -> H (3 slots)
  k2_gemm1<<<dim3(48, 32, 3), 256, 0, stream>>>(Xb, w1t, eb1, sb1, wtop, itop, Hws);
  // K3z: out = combined bias (defined base for atomics)
  k3z_bias<<<dim3(6144), 256, 0, stream>>>(sb2, eb2, wtop, itop, out);
  // K3a: sum_slots H @ W2 -> atomic accumulate into out (z = slot*2 + K-half)
  k3a_gemm2<<<dim3(48, 8, 6), 256, 0, stream>>>(Hws, w2t, wtop, itop, out);
}

// Round 4
// 707.700 us; speedup vs baseline: 1.0336x; 1.0013x over previous
//
#include <hip/hip_runtime.h>

// ---------------------------------------------------------------- types/utils
using bf16x8 = __attribute__((ext_vector_type(8))) short;
using f32x4  = __attribute__((ext_vector_type(4))) float;
using u16x4  = __attribute__((ext_vector_type(4))) unsigned short;

#define AS1(p) ((__attribute__((address_space(1))) void*)(p))
#define AS3(p) ((__attribute__((address_space(3))) void*)(p))

__device__ __forceinline__ unsigned short f2bf(float f){
  unsigned int x = __float_as_uint(f);
  unsigned int r = (x + 0x7FFFu + ((x >> 16) & 1u)) >> 16;  // RNE
  return (unsigned short)r;
}
__device__ __forceinline__ float gelu_tanh(float x){
  float u = 0.7978845608028654f * (x + 0.044715f * x * x * x);
  float t = 1.f - 2.f / (__expf(2.f * u) + 1.f);   // tanh(u)
  return 0.5f * x * (1.f + t);
}

// Problem constants
static constexpr int BB = 8, LL = 768, DD = 1024, HH = 4096, TT = 6144;

// ---------------------------------------------------------------- K0: transpose+convert (64x64 tiles)
// src (R x C) fp32 row-major -> dst (C x R) bf16 row-major. z<4: expert z, z==4: shared.
// Reads float4 (256B/row-chunk), writes u16x4 (128B per out-row segment).
__global__ __launch_bounds__(256) void k0_transpose(const float* __restrict__ srcE,
                                                    const float* __restrict__ srcS,
                                                    unsigned short* __restrict__ dst,
                                                    int R, int C){
  __shared__ float tile[64][65];
  int z = blockIdx.z;
  const float* src = (z < 4) ? srcE + (size_t)z * R * C : srcS;
  unsigned short* d = dst + (size_t)z * R * C;
  int c0 = blockIdx.x * 64, r0 = blockIdx.y * 64;
  int tx = threadIdx.x & 15, ty = threadIdx.x >> 4;   // 16x16 thread grid
  #pragma unroll
  for (int rep = 0; rep < 4; rep++){
    int r = ty + rep * 16;
    float4 v = *(const float4*)(src + (size_t)(r0 + r) * C + c0 + tx * 4);
    tile[r][tx * 4 + 0] = v.x; tile[r][tx * 4 + 1] = v.y;
    tile[r][tx * 4 + 2] = v.z; tile[r][tx * 4 + 3] = v.w;
  }
  __syncthreads();
  #pragma unroll
  for (int rep = 0; rep < 4; rep++){
    int c = ty + rep * 16;                            // out row (= src col)
    u16x4 o;
    o[0] = f2bf(tile[tx * 4 + 0][c]); o[1] = f2bf(tile[tx * 4 + 1][c]);
    o[2] = f2bf(tile[tx * 4 + 2][c]); o[3] = f2bf(tile[tx * 4 + 3][c]);
    *(u16x4*)(d + (size_t)(c0 + c) * R + r0 + tx * 4) = o;
  }
}

// ---------------------------------------------------------------- K1x: X->bf16 + segment partial sums
// One pass over X: emits Xb (bf16) and part[b][chunk(24)][d(1024)] fp32 (chunk=32 tokens).
__global__ __launch_bounds__(256) void k1x_cvt_partial(const float* __restrict__ X,
                                                       unsigned short* __restrict__ Xb,
                                                       float* __restrict__ part){
  int ch = blockIdx.x, b = blockIdx.y, t = threadIdx.x;
  size_t rowbase = ((size_t)(b * LL + ch * 32)) * DD;
  const float4* src = (const float4*)(X + rowbase);
  u16x4* dst = (u16x4*)(Xb + rowbase);
  float4 s; s.x = s.y = s.z = s.w = 0.f;
  for (int l = 0; l < 32; l++){
    float4 v = src[l * 256 + t];
    u16x4 o;
    o[0] = f2bf(v.x); o[1] = f2bf(v.y); o[2] = f2bf(v.z); o[3] = f2bf(v.w);
    dst[l * 256 + t] = o;
    s.x += v.x; s.y += v.y; s.z += v.z; s.w += v.w;
  }
  ((float4*)(part + ((size_t)(b * 24 + ch)) * DD))[t] = s;
}

// ---------------------------------------------------------------- K1b: gating finalize (fp32)
__global__ __launch_bounds__(256) void k1b_gate(const float* __restrict__ part,
                                                const float* __restrict__ tc,
                                                const float* __restrict__ gw,
                                                const float* __restrict__ gb,
                                                const float* __restrict__ tw,
                                                const float* __restrict__ tb,
                                                float* __restrict__ wtop, int* __restrict__ itop){
  int b = blockIdx.x, t = threadIdx.x;
  __shared__ float glog[4], gmod[8];
  if (t < 4) glog[t] = 0.f;
  if (t < 8) gmod[t] = 0.f;
  __syncthreads();
  float lacc[4] = {0.f,0.f,0.f,0.f};
  float macc[8] = {0.f,0.f,0.f,0.f,0.f,0.f,0.f,0.f};
  for (int dd = 0; dd < 4; dd++){
    int d = dd * 256 + t;
    const float* pb = part + (size_t)b * 24 * DD + d;
    float sh = 0.f, sw = 0.f, sp = 0.f;
    for (int c2 = 0; c2 < 8; c2++){
      sh += pb[(0  + c2) * DD];
      sw += pb[(8  + c2) * DD];
      sp += pb[(16 + c2) * DD];
    }
    float fa = (sh + sw + sp) * (1.f / 768.f);
    float hp = (sh + sp) * (1.f / 512.f);
    float wp = (sw + sp) * (1.f / 512.f);
    #pragma unroll
    for (int e = 0; e < 4; e++){
      lacc[e] += fa * gw[(size_t)d * 4 + e]
               + hp * gw[(size_t)(DD + d) * 4 + e]
               + wp * gw[(size_t)(2 * DD + d) * 4 + e];
    }
    float v = tc[(size_t)b * DD + d];
    float sl = v / (1.f + __expf(-v));           // silu
    #pragma unroll
    for (int j = 0; j < 8; j++) macc[j] += sl * tw[(size_t)d * 8 + j];
  }
  #pragma unroll
  for (int e = 0; e < 4; e++) atomicAdd(&glog[e], lacc[e]);
  #pragma unroll
  for (int j = 0; j < 8; j++) atomicAdd(&gmod[j], macc[j]);
  __syncthreads();
  if (t == 0){
    float lg[4];
    #pragma unroll
    for (int e = 0; e < 4; e++){
      float sc = gmod[e]     + tb[e];      // scale
      float sf = gmod[4 + e] + tb[4 + e];  // shift
      lg[e] = (glog[e] + gb[e]) * (1.f + sc) + sf;
    }
    float mx = fmaxf(fmaxf(lg[0], lg[1]), fmaxf(lg[2], lg[3]));
    float p[4], s = 0.f;
    #pragma unroll
    for (int e = 0; e < 4; e++){ p[e] = __expf(lg[e] - mx); s += p[e]; }
    #pragma unroll
    for (int e = 0; e < 4; e++) p[e] /= s;
    int i0 = 0;
    for (int e = 1; e < 4; e++) if (p[e] > p[i0]) i0 = e;
    int i1 = (i0 == 0) ? 1 : 0;
    for (int e = 0; e < 4; e++) if (e != i0 && p[e] > p[i1]) i1 = e;
    float den = p[i0] + p[i1] + 1e-8f;
    wtop[b * 2 + 0] = p[i0] / den;  wtop[b * 2 + 1] = p[i1] / den;
    itop[b * 2 + 0] = i0;           itop[b * 2 + 1] = i1;
  }
}

// ---------------------------------------------------------------- GEMM core
// C(128x128) += A(128 x 64*nkt) * B^T; A rows K-contig (lda), B rows (=output
// cols) K-contig (ldb). Both bf16. 256 thr = 4 waves 2x2; wave tile 64x64 =
// 4x4 MFMA 16x16x32 tiles. LDS cell = 16B; XOR swizzle c^=(m&7) so the
// fragment ds_read_b128 is 2-way bank aliased (free) instead of 16-way.
__device__ __forceinline__ void gemm_core(const unsigned short* __restrict__ A,
                                          const unsigned short* __restrict__ B,
                                          size_t lda, size_t ldb, int nkt,
                                          unsigned short* ldsA, unsigned short* ldsB,
                                          f32x4 (&acc)[4][4]){
  int tid = threadIdx.x;
  int lane = tid & 63, wave = tid >> 6;
  int quad = lane >> 4, r = lane & 15;
  int wm = (wave >> 1) * 64, wn = (wave & 1) * 64;
  int wavebase = tid & 192;                       // wave*64, wave-uniform
  for (int kt = 0; kt < nkt; kt++){
    int k0 = kt * 64;
    #pragma unroll
    for (int i = 0; i < 4; i++){
      int g = i * 256 + tid;                      // cell index [0,1024)
      int m = g >> 3, slot = g & 7;
      int c = slot ^ (m & 7);
      const unsigned short* gpA = A + (size_t)m * lda + (k0 + c * 8);
      const unsigned short* gpB = B + (size_t)m * ldb + (k0 + c * 8);
      unsigned short* lp = ldsA + (size_t)(i * 256 + wavebase) * 8; // wave-uniform
      __builtin_amdgcn_global_load_lds(AS1(gpA), AS3(lp), 16, 0, 0);
      unsigned short* lq = ldsB + (size_t)(i * 256 + wavebase) * 8;
      __builtin_amdgcn_global_load_lds(AS1(gpB), AS3(lq), 16, 0, 0);
    }
    __syncthreads();
    #pragma unroll
    for (int ks = 0; ks < 2; ks++){
      int cc = ks * 4 + quad;
      bf16x8 af[4], bfv[4];
      #pragma unroll
      for (int t2 = 0; t2 < 4; t2++){
        int m = wm + t2 * 16 + r;
        af[t2] = *(const bf16x8*)(ldsA + ((size_t)m * 8 + (cc ^ (m & 7))) * 8);
        int n = wn + t2 * 16 + r;
        bfv[t2] = *(const bf16x8*)(ldsB + ((size_t)n * 8 + (cc ^ (n & 7))) * 8);
      }
      #pragma unroll
      for (int mi = 0; mi < 4; mi++)
        #pragma unroll
        for (int ni = 0; ni < 4; ni++)
          acc[mi][ni] = __builtin_amdgcn_mfma_f32_16x16x32_bf16(af[mi], bfv[ni], acc[mi][ni], 0, 0, 0);
    }
    __syncthreads();
  }
}

__device__ __forceinline__ void mask_weight(int e, int seg, float& w){
  if ((e == 1 && seg == 1) || (e == 2 && seg == 0)) w = 0.f;
}

// ---------------------------------------------------------------- K2: GEMM1 + gelu
// H[slot][token][h] = w_eff * gelu(X @ W1 + b1). slot0=shared(w=1), slot1/2=topk.
__global__ __launch_bounds__(256) void k2_gemm1(const unsigned short* __restrict__ Xb,
                                                const unsigned short* __restrict__ w1t,
                                                const float* __restrict__ eb1,
                                                const float* __restrict__ sb1,
                                                const float* __restrict__ wtop,
                                                const int* __restrict__ itop,
                                                unsigned short* __restrict__ Hws){
  int m0 = blockIdx.x * 128, n0 = blockIdx.y * 128, slot = blockIdx.z;
  int b = m0 / LL, seg = (m0 % LL) / 256;
  int mat; float w;
  if (slot == 0){ mat = 4; w = 1.f; }
  else {
    int k = slot - 1;
    mat = itop[b * 2 + k];
    w = wtop[b * 2 + k];
    mask_weight(mat, seg, w);
    if (w == 0.f) return;  // K3a skips this (m-tile, slot) with the same predicate
  }
  __shared__ __align__(16) unsigned short ldsA[128 * 64];
  __shared__ __align__(16) unsigned short ldsB[128 * 64];
  f32x4 acc[4][4];
  #pragma unroll
  for (int mi = 0; mi < 4; mi++)
    #pragma unroll
    for (int ni = 0; ni < 4; ni++)
      #pragma unroll
      for (int c = 0; c < 4; c++) acc[mi][ni][c] = 0.f;

  const unsigned short* Abase = Xb + (size_t)m0 * DD;
  const unsigned short* Bbase = w1t + (size_t)mat * HH * DD + (size_t)n0 * DD;
  gemm_core(Abase, Bbase, DD, DD, DD / 64, ldsA, ldsB, acc);

  int tid = threadIdx.x, lane = tid & 63, wave = tid >> 6;
  int quad = lane >> 4, r = lane & 15;
  int wm = (wave >> 1) * 64, wn = (wave & 1) * 64;
  const float* b1 = (mat == 4) ? sb1 : eb1 + (size_t)mat * HH;
  unsigned short* Hout = Hws + (size_t)slot * TT * HH;
  #pragma unroll
  for (int ni = 0; ni < 4; ni++){
    int col = n0 + wn + ni * 16 + r;
    float bias = b1[col];
    #pragma unroll
    for (int mi = 0; mi < 4; mi++){
      #pragma unroll
      for (int r2 = 0; r2 < 4; r2++){
        int row = m0 + wm + mi * 16 + quad * 4 + r2;
        float v = gelu_tanh(acc[mi][ni][r2] + bias) * w;
        Hout[(size_t)row * HH + col] = f2bf(v);
      }
    }
  }
}

// ---------------------------------------------------------------- K3a: GEMM2, slots in-block, z=K-half
// kh=0 writes out = acc + combined bias (sole writer); kh=1 writes partial p1.
__global__ __launch_bounds__(256) void k3a_gemm2(const unsigned short* __restrict__ Hws,
                                                 const unsigned short* __restrict__ w2t,
                                                 const float* __restrict__ eb2,
                                                 const float* __restrict__ sb2,
                                                 const float* __restrict__ wtop,
                                                 const int* __restrict__ itop,
                                                 float* __restrict__ out,
                                                 float* __restrict__ p1){
  int m0 = blockIdx.x * 128, n0 = blockIdx.y * 128, kh = blockIdx.z;
  int b = m0 / LL, seg = (m0 % LL) / 256;
  __shared__ __align__(16) unsigned short ldsA[128 * 64];
  __shared__ __align__(16) unsigned short ldsB[128 * 64];
  f32x4 acc[4][4];
  #pragma unroll
  for (int mi = 0; mi < 4; mi++)
    #pragma unroll
    for (int ni = 0; ni < 4; ni++)
      #pragma unroll
      for (int c = 0; c < 4; c++) acc[mi][ni][c] = 0.f;

  int emat[2]; float ew[2];
  #pragma unroll
  for (int k = 0; k < 2; k++){
    emat[k] = itop[b * 2 + k];
    ew[k] = wtop[b * 2 + k];
    mask_weight(emat[k], seg, ew[k]);
  }
  for (int slot = 0; slot < 3; slot++){
    int mat;
    if (slot == 0) mat = 4;
    else { if (ew[slot - 1] == 0.f) continue; mat = emat[slot - 1]; }  // matches K2 skip
    const unsigned short* Abase = Hws + (size_t)slot * TT * HH + (size_t)m0 * HH + kh * 2048;
    const unsigned short* Bbase = w2t + (size_t)mat * DD * HH + (size_t)n0 * HH + kh * 2048;
    gemm_core(Abase, Bbase, HH, HH, 2048 / 64, ldsA, ldsB, acc);
  }
  int tid = threadIdx.x, lane = tid & 63, wave = tid >> 6;
  int quad = lane >> 4, r = lane & 15;
  int wm = (wave >> 1) * 64, wn = (wave & 1) * 64;
  if (kh == 0){
    #pragma unroll
    for (int ni = 0; ni < 4; ni++){
      int col = n0 + wn + ni * 16 + r;
      float bias = sb2[col];
      if (ew[0] > 0.f) bias += ew[0] * eb2[(size_t)emat[0] * DD + col];
      if (ew[1] > 0.f) bias += ew[1] * eb2[(size_t)emat[1] * DD + col];
      #pragma unroll
      for (int mi = 0; mi < 4; mi++)
        #pragma unroll
        for (int r2 = 0; r2 < 4; r2++){
          int row = m0 + wm + mi * 16 + quad * 4 + r2;
          out[(size_t)row * DD + col] = acc[mi][ni][r2] + bias;
        }
    }
  } else {
    #pragma unroll
    for (int ni = 0; ni < 4; ni++){
      int col = n0 + wn + ni * 16 + r;
      #pragma unroll
      for (int mi = 0; mi < 4; mi++)
        #pragma unroll
        for (int r2 = 0; r2 < 4; r2++){
          int row = m0 + wm + mi * 16 + quad * 4 + r2;
          p1[(size_t)row * DD + col] = acc[mi][ni][r2];
        }
    }
  }
}

// ---------------------------------------------------------------- K3r: out += p1
__global__ __launch_bounds__(256) void k3r_reduce(float* __restrict__ out,
                                                  const float* __restrict__ p1){
  size_t i = (size_t)blockIdx.x * 256 + threadIdx.x;
  float4 a = ((const float4*)out)[i];
  float4 b = ((const float4*)p1)[i];
  a.x += b.x; a.y += b.y; a.z += b.z; a.w += b.w;
  ((float4*)out)[i] = a;
}

// ---------------------------------------------------------------- launch
extern "C" void kernel_launch(void* const* d_in, const int* in_sizes, int n_in,
                              void* d_out, int out_size, void* d_ws, size_t ws_size,
                              hipStream_t stream){
  const float* X   = (const float*)d_in[0];   // context_c (8,768,1024)
  const float* tc  = (const float*)d_in[1];   // time_cond (8,1024)
  const float* gw  = (const float*)d_in[2];   // gate_w (3072,4)
  const float* gb  = (const float*)d_in[3];   // gate_b (4)
  const float* tw  = (const float*)d_in[4];   // time_w (1024,8)
  const float* tb  = (const float*)d_in[5];   // time_b (8)
  const float* ew1 = (const float*)d_in[6];   // (4,1024,4096)
  const float* eb1 = (const float*)d_in[7];   // (4,4096)
  const float* ew2 = (const float*)d_in[8];   // (4,4096,1024)
  const float* eb2 = (const float*)d_in[9];   // (4,1024)
  const float* sw1 = (const float*)d_in[10];  // (1024,4096)
  const float* sb1 = (const float*)d_in[11];  // (4096)
  const float* sw2 = (const float*)d_in[12];  // (4096,1024)
  const float* sb2 = (const float*)d_in[13];  // (1024)
  float* out = (float*)d_out;
  char* ws = (char*)d_ws;

  const size_t off_part = 0;                         // 8*24*1024*4 = 786432
  const size_t off_wtop = 786432;                    // 64 B
  const size_t off_itop = 786560;                    // 64 B
  const size_t off_xb   = 1ull << 20;                // 6144*1024*2 = 12,582,912
  const size_t off_w1t  = 14ull << 20;               // 5*4096*1024*2 = 41,943,040
  const size_t off_w2t  = off_w1t + 41943040ull;     // 41,943,040
  const size_t off_h    = off_w2t + 41943040ull;     // 3*6144*4096*2 = 150,994,944
  const size_t need     = off_h + 150994944ull;      // ~238 MiB
  if (ws_size < need) return;  // diagnostic: reproduces stub absmax 3.34375 if ws too small

  float* part = (float*)(ws + off_part);
  float* wtop = (float*)(ws + off_wtop);
  int*   itop = (int*)(ws + off_itop);
  unsigned short* Xb  = (unsigned short*)(ws + off_xb);
  unsigned short* w1t = (unsigned short*)(ws + off_w1t);
  unsigned short* w2t = (unsigned short*)(ws + off_w2t);
  unsigned short* Hws = (unsigned short*)(ws + off_h);
  float* p1 = (float*)(ws + off_w1t);  // aliases w1t: dead after k2, reused by k3a (stream-ordered)

  // K1x: X fp32 -> bf16 + gating partial sums (single pass over X)
  k1x_cvt_partial<<<dim3(24, 8), 256, 0, stream>>>(X, Xb, part);
  // K0: weight transpose+convert (W1: 1024x4096 -> 4096x1024; W2: 4096x1024 -> 1024x4096)
  k0_transpose<<<dim3(64, 16, 5), 256, 0, stream>>>(ew1, sw1, w1t, 1024, 4096);
  k0_transpose<<<dim3(16, 64, 5), 256, 0, stream>>>(ew2, sw2, w2t, 4096, 1024);
  // K1b: gating finalize (fp32 exact)
  k1b_gate<<<dim3(8), 256, 0, stream>>>(part, tc, gw, gb, tw, tb, wtop, itop);
  // K2: X @ W1 + b1 -> gelu -> *w_eff -> H (3 slots)
  k2_gemm1<<<dim3(48, 32, 3), 256, 0, stream>>>(Xb, w1t, eb1, sb1, wtop, itop, Hws);
  // K3a: slots in-block, z = K-half; kh=0 -> out(+bias), kh=1 -> p1. 768 blocks = 3/CU, tail-free.
  k3a_gemm2<<<dim3(48, 8, 2), 256, 0, stream>>>(Hws, w2t, eb2, sb2, wtop, itop, out, p1);
  // K3r: out += p1
  k3r_reduce<<<dim3(6144), 256, 0, stream>>>(out, p1);
}